// Round 6
// baseline (6200.713 us; speedup 1.0000x reference)
//
#include <hip/hip_runtime.h>
#include <cstddef>

// Problem constants
#define Bb 128
#define Tt 512
#define Ii 256
#define Hh 512
#define G4c 2048      // 4*H
#define BHc (Bb * Hh) // elements in one h buffer

typedef float    f32x4 __attribute__((ext_vector_type(4)));
typedef _Float16 f16x8 __attribute__((ext_vector_type(8)));
typedef unsigned int u32x4 __attribute__((ext_vector_type(4)));

// ws layout (bytes)
#define OFF_WT1 0u
#define OFF_WT2 3145728u          // 32jb*24ks*4g*64ln*8i*2B
#define OFF_BC1 7340032u          // +32jb*32ks*4g*64ln*8i*2B
#define OFF_BC2 7348224u
#define OFF_H1  7356416u          // 3 slots * 128*512*2
#define OFF_H2  7749632u          // 2 slots * 128*512*2
#define OFF_FLG 8011776u          // 128 u32: [rh*64 + layer*32 + jb]
#define OFF_END 8012288u

__device__ __forceinline__ float sigm(float x)  { return 1.0f / (1.0f + __expf(-x)); }
__device__ __forceinline__ float tanhf_(float x){ return 1.0f - 2.0f / (1.0f + __expf(2.0f * x)); }

// ---- memory ops ----
// sc0: bypass per-CU L1, served by (post-inv) L2 -> shared L3 fetches per XCD
__device__ __forceinline__ void ld_g_f16x8_sc0(f16x8& dst, const _Float16* p) {
  asm volatile("global_load_dwordx4 %0, %1, off sc0" : "=v"(dst) : "v"(p) : "memory");
}
__device__ __forceinline__ void ld_g_f32x4(f32x4& dst, const float* p) {
  asm volatile("global_load_dwordx4 %0, %1, off" : "=v"(dst) : "v"(p) : "memory");
}
__device__ __forceinline__ void st_g_f16_sc(_Float16* p, _Float16 v) {
  unsigned u = (unsigned)__builtin_bit_cast(unsigned short, v);
  asm volatile("global_store_short %0, %1, off sc0 sc1" :: "v"(p), "v"(u) : "memory");
}
__device__ __forceinline__ void wait_vm0() {
  asm volatile("s_waitcnt vmcnt(0)" ::: "memory");
}
__device__ __forceinline__ void l2_inv() {   // agent-acquire: invalidate XCD L2
  asm volatile("buffer_inv sc1" ::: "memory");
}

// Wait: lanes 0-31 watch base[0..31] (layer1 flags) vs tgtA;
//       lanes 32-63 watch base[32..63] (layer2 flags) vs tgtB.
__device__ __forceinline__ void poll2(unsigned* base, int tid,
                                      unsigned tgtA, unsigned tgtB) {
  if (tid < 64) {
    const unsigned tgt = (tid < 32) ? tgtA : tgtB;
    unsigned v;
    do {
      v = __hip_atomic_load(base + tid, __ATOMIC_RELAXED, __HIP_MEMORY_SCOPE_AGENT);
    } while (__any(v < tgt));
  }
  __syncthreads();
}

// Publish: drain own sc stores (per-wave), block-sync, set own flag.
__device__ __forceinline__ void publish(unsigned* myflag, int tid, unsigned val) {
  wait_vm0();
  __syncthreads();
  if (tid == 0)
    __hip_atomic_store(myflag, val, __ATOMIC_RELAXED, __HIP_MEMORY_SCOPE_AGENT);
}

// Pack weights FRAGMENT-MAJOR (round-5 proven): WtF[jb][ks][g][lane][i] =
//   W_cat[k = ks*32 + (lane>>4)*8 + i][gcol = g*512 + jb*16 + (lane&15)]
__global__ void init_weights(const float* __restrict__ Wx1, const float* __restrict__ Wh1,
                             const float* __restrict__ bx1, const float* __restrict__ bh1,
                             const float* __restrict__ Wx2, const float* __restrict__ Wh2,
                             const float* __restrict__ bx2, const float* __restrict__ bh2,
                             _Float16* __restrict__ Wt1, _Float16* __restrict__ Wt2,
                             float* __restrict__ bc1, float* __restrict__ bc2) {
  const int b = blockIdx.x;
  const int layer = b >> 11;
  const int jb = (b >> 6) & 31;
  const int ln = b & 63;
  const int t  = threadIdx.x;
  const int ks = t >> 3;
  const int i  = t & 7;
  const int k  = (ks << 5) + ((ln >> 4) << 3) + i;
  if (layer == 0) {
    if (ln == 0 && t < 16) {
      #pragma unroll
      for (int g = 0; g < 4; ++g) {
        const int gc = (g << 9) + (jb << 4) + t;
        bc1[gc] = bx1[gc] + bh1[gc];
      }
    }
    if (ks < 24) {
      #pragma unroll
      for (int g = 0; g < 4; ++g) {
        const int gc = (g << 9) + (jb << 4) + (ln & 15);
        const float v = (k < Ii) ? Wx1[k * G4c + gc] : Wh1[(k - Ii) * G4c + gc];
        Wt1[((((size_t)jb * 24 + ks) * 4 + g) * 64 + ln) * 8 + i] = (_Float16)v;
      }
    }
  } else {
    if (ln == 0 && t < 16) {
      #pragma unroll
      for (int g = 0; g < 4; ++g) {
        const int gc = (g << 9) + (jb << 4) + t;
        bc2[gc] = bx2[gc] + bh2[gc];
      }
    }
    #pragma unroll
    for (int g = 0; g < 4; ++g) {
      const int gc = (g << 9) + (jb << 4) + (ln & 15);
      const float v = (k < Hh) ? Wx2[k * G4c + gc] : Wh2[(k - Hh) * G4c + gc];
      Wt2[((((size_t)jb * 32 + ks) * 4 + g) * 64 + ln) * 8 + i] = (_Float16)v;
    }
  }
}

__global__ void zero_ws(u32x4* p, int n) {
  const int i = blockIdx.x * blockDim.x + threadIdx.x;
  if (i < n) p[i] = (u32x4){0u, 0u, 0u, 0u};
}

// Persistent cooperative kernel (round-5 compute; wait-at-start sync).
// 128 blocks: bid>>6 = layer; blkL = bid&63; jb = blkL>>1; rh = blkL&1.
// Flags: monotonic per-block epoch counters, f = e+1 after finishing epoch e.
// layer1@e waits [L1>=e && L2>=e-1] (3-slot h1 gives the 1-epoch lag);
// layer2@e waits [L1>=e && L2>=e].
__global__ __launch_bounds__(256, 1) void lstm_main(
    const float* __restrict__ x,
    const _Float16* __restrict__ Wt1, const _Float16* __restrict__ Wt2,
    const float* __restrict__ bc1, const float* __restrict__ bc2,
    _Float16* h1buf, _Float16* h2buf, unsigned* flags,
    const float* __restrict__ Whead, const float* __restrict__ bhead,
    float* __restrict__ out)
{
  extern __shared__ char smem[];

  const int tid  = threadIdx.x;
  const int lane = tid & 63;
  const int wv   = tid >> 6;
  const int bid  = blockIdx.x;
  const int layer = bid >> 6;
  const int blkL  = bid & 63;
  const int jb = blkL >> 1;
  const int rh = blkL & 1;
  const int j0 = jb << 4;

  unsigned* grp = flags + (rh << 6);
  unsigned* myflag = grp + (layer << 5) + jb;

  // ---- stage fragment-major weight slice into LDS (flat copy) ----
  {
    const int elems16 = layer ? (131072 / 16) : (98304 / 16);
    const u32x4* src = (const u32x4*)((layer ? Wt2 : Wt1)
                                      + (size_t)jb * (layer ? 65536 : 49152));
    u32x4* dst = (u32x4*)smem;
    for (int i = tid; i < elems16; i += 256) dst[i] = src[i];
  }
  __syncthreads();

  const int c15 = lane & 15;
  const int kg  = lane >> 4;
  const int arow  = (rh << 6) + (wv << 4) + c15;
  const int wrow0 = (rh << 6) + (wv << 4) + (kg << 2);

  const float* bc = layer ? bc2 : bc1;
  const float bias0 = bc[        j0 + c15];
  const float bias1 = bc[ 512 +  j0 + c15];
  const float bias2 = bc[1024 +  j0 + c15];
  const float bias3 = bc[1536 +  j0 + c15];

  const int lb = lane << 4;

  f32x4 cst = {0.f, 0.f, 0.f, 0.f};

  int m3w = 0;   // e % 3       (h1 write slot)
  int m3r = 2;   // (e-1) % 3   (h1 read slot)

  for (int e = 0; e <= Tt; ++e) {
    if (layer == 0) {
      if (e >= Tt) break;   // layer1 done (published 512 at e=511)
      // 1. x prefetch BEFORE the wait (barrier-independent)
      f32x4 xf[16];
      const float* xp = x + (size_t)arow * (Tt * Ii) + (size_t)e * Ii + (kg << 3);
      #pragma unroll
      for (int ks = 0; ks < 8; ++ks) {
        ld_g_f32x4(xf[2*ks],   xp + (ks << 5));
        ld_g_f32x4(xf[2*ks+1], xp + (ks << 5) + 4);
      }
      // 2. wait for producers
      poll2(grp, tid, (unsigned)e, e ? (unsigned)(e - 1) : 0u);
      // 3. acquire + h1(e-1) loads (sc0: L1-bypass, L2-shared)
      l2_inv();
      f16x8 af[24];
      const _Float16* hp = h1buf + (size_t)m3r * BHc + arow * Hh + (kg << 3);
      #pragma unroll
      for (int ks = 0; ks < 16; ++ks)
        ld_g_f16x8_sc0(af[8 + ks], hp + (ks << 5));
      wait_vm0();
      __builtin_amdgcn_sched_barrier(0);
      #pragma unroll
      for (int ks = 0; ks < 8; ++ks) {
        f16x8 v;
        v[0] = (_Float16)xf[2*ks][0]; v[1] = (_Float16)xf[2*ks][1];
        v[2] = (_Float16)xf[2*ks][2]; v[3] = (_Float16)xf[2*ks][3];
        v[4] = (_Float16)xf[2*ks+1][0]; v[5] = (_Float16)xf[2*ks+1][1];
        v[6] = (_Float16)xf[2*ks+1][2]; v[7] = (_Float16)xf[2*ks+1][3];
        af[ks] = v;
      }
      f32x4 acc0 = {0.f,0.f,0.f,0.f}, acc1 = {0.f,0.f,0.f,0.f};
      f32x4 acc2 = {0.f,0.f,0.f,0.f}, acc3 = {0.f,0.f,0.f,0.f};
      #pragma unroll
      for (int ks = 0; ks < 24; ++ks) {
        const char* bp = smem + (ks << 12) + lb;
        acc0 = __builtin_amdgcn_mfma_f32_16x16x32_f16(af[ks], *(const f16x8*)(bp       ), acc0, 0, 0, 0);
        acc1 = __builtin_amdgcn_mfma_f32_16x16x32_f16(af[ks], *(const f16x8*)(bp + 1024), acc1, 0, 0, 0);
        acc2 = __builtin_amdgcn_mfma_f32_16x16x32_f16(af[ks], *(const f16x8*)(bp + 2048), acc2, 0, 0, 0);
        acc3 = __builtin_amdgcn_mfma_f32_16x16x32_f16(af[ks], *(const f16x8*)(bp + 3072), acc3, 0, 0, 0);
      }
      float hout[4];
      #pragma unroll
      for (int r = 0; r < 4; ++r) {
        const float iv = sigm(acc0[r] + bias0);
        const float fv = sigm(acc1[r] + bias1);
        const float gv = tanhf_(acc2[r] + bias2);
        const float ov = sigm(acc3[r] + bias3);
        const float cv = fv * cst[r] + iv * gv;
        cst[r] = cv;
        hout[r] = ov * tanhf_(cv);
      }
      _Float16* hw = h1buf + (size_t)m3w * BHc;
      #pragma unroll
      for (int r = 0; r < 4; ++r)
        st_g_f16_sc(hw + (size_t)(wrow0 + r) * Hh + j0 + c15, (_Float16)hout[r]);
      publish(myflag, tid, (unsigned)(e + 1));
    } else {
      if (e == 0) {
        publish(myflag, tid, 1u);
      } else {
        poll2(grp, tid, (unsigned)e, (unsigned)e);
        l2_inv();
        f16x8 af[32];
        const _Float16* h1p = h1buf + (size_t)m3r * BHc + arow * Hh + (kg << 3);
        const _Float16* h2p = h2buf + (size_t)(e & 1) * BHc + arow * Hh + (kg << 3);
        #pragma unroll
        for (int ks = 0; ks < 16; ++ks)
          ld_g_f16x8_sc0(af[ks], h1p + (ks << 5));
        #pragma unroll
        for (int ks = 0; ks < 16; ++ks)
          ld_g_f16x8_sc0(af[16 + ks], h2p + (ks << 5));
        wait_vm0();
        __builtin_amdgcn_sched_barrier(0);
        f32x4 acc0 = {0.f,0.f,0.f,0.f}, acc1 = {0.f,0.f,0.f,0.f};
        f32x4 acc2 = {0.f,0.f,0.f,0.f}, acc3 = {0.f,0.f,0.f,0.f};
        #pragma unroll
        for (int ks = 0; ks < 32; ++ks) {
          const char* bp = smem + (ks << 12) + lb;
          acc0 = __builtin_amdgcn_mfma_f32_16x16x32_f16(af[ks], *(const f16x8*)(bp       ), acc0, 0, 0, 0);
          acc1 = __builtin_amdgcn_mfma_f32_16x16x32_f16(af[ks], *(const f16x8*)(bp + 1024), acc1, 0, 0, 0);
          acc2 = __builtin_amdgcn_mfma_f32_16x16x32_f16(af[ks], *(const f16x8*)(bp + 2048), acc2, 0, 0, 0);
          acc3 = __builtin_amdgcn_mfma_f32_16x16x32_f16(af[ks], *(const f16x8*)(bp + 3072), acc3, 0, 0, 0);
        }
        float hout[4];
        #pragma unroll
        for (int r = 0; r < 4; ++r) {
          const float iv = sigm(acc0[r] + bias0);
          const float fv = sigm(acc1[r] + bias1);
          const float gv = tanhf_(acc2[r] + bias2);
          const float ov = sigm(acc3[r] + bias3);
          const float cv = fv * cst[r] + iv * gv;
          cst[r] = cv;
          hout[r] = ov * tanhf_(cv);
        }
        _Float16* hw = h2buf + (size_t)((e + 1) & 1) * BHc;
        #pragma unroll
        for (int r = 0; r < 4; ++r)
          st_g_f16_sc(hw + (size_t)(wrow0 + r) * Hh + j0 + c15, (_Float16)hout[r]);
        publish(myflag, tid, (unsigned)(e + 1));
      }
    }
    m3w = (m3w + 1 == 3) ? 0 : m3w + 1;
    m3r = (m3r + 1 == 3) ? 0 : m3r + 1;
  }

  // head: out[b][c] = h2_T[b,:] . W_head[:,c] + b_head[c]; h2_T = h2buf slot 1 (fp16)
  if (layer == 1 && jb == 0) {
    poll2(grp, tid, 0u, 513u);   // all layer2 blocks published final epoch
    l2_inv();
    const int b_ = (rh << 6) + (tid >> 2);
    const int cc = tid & 3;
    const _Float16* hr = h2buf + BHc + (size_t)b_ * Hh;
    float s = bhead[cc];
    #pragma unroll
    for (int half = 0; half < 2; ++half) {
      f16x8 hv[32];
      #pragma unroll
      for (int kk = 0; kk < 32; ++kk)
        ld_g_f16x8_sc0(hv[kk], hr + (half << 8) + (kk << 3));
      wait_vm0();
      #pragma unroll
      for (int kk = 0; kk < 32; ++kk) {
        const int k = (half << 8) + (kk << 3);
        #pragma unroll
        for (int j = 0; j < 8; ++j)
          s += (float)hv[kk][j] * Whead[(k + j) * 4 + cc];
      }
    }
    out[b_ * 4 + cc] = s;
  }
}

extern "C" void kernel_launch(void* const* d_in, const int* in_sizes, int n_in,
                              void* d_out, int out_size, void* d_ws, size_t ws_size,
                              hipStream_t stream) {
  const float* x   = (const float*)d_in[0];
  const float* Wx1 = (const float*)d_in[1];
  const float* bx1 = (const float*)d_in[2];
  const float* Wh1 = (const float*)d_in[3];
  const float* bh1 = (const float*)d_in[4];
  const float* Wx2 = (const float*)d_in[5];
  const float* bx2 = (const float*)d_in[6];
  const float* Wh2 = (const float*)d_in[7];
  const float* bh2 = (const float*)d_in[8];
  const float* Whd = (const float*)d_in[9];
  const float* bhd = (const float*)d_in[10];

  char* ws = (char*)d_ws;
  _Float16* Wt1 = (_Float16*)(ws + OFF_WT1);
  _Float16* Wt2 = (_Float16*)(ws + OFF_WT2);
  float* bc1 = (float*)(ws + OFF_BC1);
  float* bc2 = (float*)(ws + OFF_BC2);
  _Float16* h1b = (_Float16*)(ws + OFF_H1);
  _Float16* h2b = (_Float16*)(ws + OFF_H2);
  unsigned* flg = (unsigned*)(ws + OFF_FLG);
  float* out = (float*)d_out;

  init_weights<<<4096, 256, 0, stream>>>(Wx1, Wh1, bx1, bh1, Wx2, Wh2, bx2, bh2,
                                         Wt1, Wt2, bc1, bc2);
  {
    u32x4* zp = (u32x4*)(ws + OFF_H1);
    const int n = (int)((OFF_END - OFF_H1) / 16);  // zero h buffers + flags
    zero_ws<<<(n + 255) / 256, 256, 0, stream>>>(zp, n);
  }
  (void)hipFuncSetAttribute((const void*)lstm_main,
                            hipFuncAttributeMaxDynamicSharedMemorySize, 131072);
  void* args[] = {(void*)&x, (void*)&Wt1, (void*)&Wt2, (void*)&bc1, (void*)&bc2,
                  (void*)&h1b, (void*)&h2b, (void*)&flg,
                  (void*)&Whd, (void*)&bhd, (void*)&out};
  (void)hipLaunchCooperativeKernel((const void*)lstm_main, dim3(128), dim3(256),
                                   args, 131072, stream);
}

// Round 7
// 3982.552 us; speedup vs baseline: 1.5570x; 1.5570x over previous
//
#include <hip/hip_runtime.h>
#include <cstddef>

// Problem constants
#define Bb 128
#define Tt 512
#define Ii 256
#define Hh 512
#define G4c 2048      // 4*H
#define BHc (Bb * Hh) // elements in one h buffer
#define FSTRIDE 32    // u32s per flag (128B line each)

typedef float    f32x4 __attribute__((ext_vector_type(4)));
typedef _Float16 f16x8 __attribute__((ext_vector_type(8)));
typedef unsigned int u32x4 __attribute__((ext_vector_type(4)));

// ws layout (bytes)
#define OFF_WT1 0u
#define OFF_WT2 3145728u          // 32jb*24ks*4g*64ln*8i*2B
#define OFF_BC1 7340032u          // +32jb*32ks*4g*64ln*8i*2B
#define OFF_BC2 7348224u
#define OFF_H1  7356416u          // 3 slots * 128*512*2
#define OFF_H2  7749632u          // 2 slots * 128*512*2
#define OFF_FLG 8011776u          // 128 flags * 128B  [rh*64 + layer*32 + jb]
#define OFF_END 8028160u

__device__ __forceinline__ float sigm(float x)  { return 1.0f / (1.0f + __expf(-x)); }
__device__ __forceinline__ float tanhf_(float x){ return 1.0f - 2.0f / (1.0f + __expf(2.0f * x)); }

// ---- coherent (cross-XCD) memory ops: bypass non-coherent L2 via sc0 sc1 ----
__device__ __forceinline__ void ld_g_f16x8_sc(f16x8& dst, const _Float16* p) {
  asm volatile("global_load_dwordx4 %0, %1, off sc0 sc1"
               : "=v"(dst) : "v"(p) : "memory");
}
__device__ __forceinline__ void ld_g_f32x4(f32x4& dst, const float* p) {
  asm volatile("global_load_dwordx4 %0, %1, off" : "=v"(dst) : "v"(p) : "memory");
}
__device__ __forceinline__ void st_g_f16_sc(_Float16* p, _Float16 v) {
  unsigned u = (unsigned)__builtin_bit_cast(unsigned short, v);
  asm volatile("global_store_short %0, %1, off sc0 sc1" :: "v"(p), "v"(u) : "memory");
}
__device__ __forceinline__ void wait_vm0() {
  asm volatile("s_waitcnt vmcnt(0)" ::: "memory");
}

// Wait: lanes 0-31 watch L1 flags vs tgtA; lanes 32-63 watch L2 flags vs tgtB.
// Flags padded to one 128B line each -> no same-line contention between flags.
__device__ __forceinline__ void poll2(unsigned* base, int tid,
                                      unsigned tgtA, unsigned tgtB) {
  if (tid < 64) {
    const unsigned tgt = (tid < 32) ? tgtA : tgtB;
    unsigned* p = base + (size_t)tid * FSTRIDE;
    unsigned v;
    do {
      v = __hip_atomic_load(p, __ATOMIC_RELAXED, __HIP_MEMORY_SCOPE_AGENT);
    } while (__any(v < tgt));
  }
  __syncthreads();
}

// Publish: drain own sc stores (per-wave), block-sync, set own flag.
__device__ __forceinline__ void publish(unsigned* myflag, int tid, unsigned val) {
  wait_vm0();
  __syncthreads();
  if (tid == 0)
    __hip_atomic_store(myflag, val, __ATOMIC_RELAXED, __HIP_MEMORY_SCOPE_AGENT);
}

// Pack weights FRAGMENT-MAJOR (round-5 proven): WtF[jb][ks][g][lane][i] =
//   W_cat[k = ks*32 + (lane>>4)*8 + i][gcol = g*512 + jb*16 + (lane&15)]
__global__ void init_weights(const float* __restrict__ Wx1, const float* __restrict__ Wh1,
                             const float* __restrict__ bx1, const float* __restrict__ bh1,
                             const float* __restrict__ Wx2, const float* __restrict__ Wh2,
                             const float* __restrict__ bx2, const float* __restrict__ bh2,
                             _Float16* __restrict__ Wt1, _Float16* __restrict__ Wt2,
                             float* __restrict__ bc1, float* __restrict__ bc2) {
  const int b = blockIdx.x;
  const int layer = b >> 11;
  const int jb = (b >> 6) & 31;
  const int ln = b & 63;
  const int t  = threadIdx.x;
  const int ks = t >> 3;
  const int i  = t & 7;
  const int k  = (ks << 5) + ((ln >> 4) << 3) + i;
  if (layer == 0) {
    if (ln == 0 && t < 16) {
      #pragma unroll
      for (int g = 0; g < 4; ++g) {
        const int gc = (g << 9) + (jb << 4) + t;
        bc1[gc] = bx1[gc] + bh1[gc];
      }
    }
    if (ks < 24) {
      #pragma unroll
      for (int g = 0; g < 4; ++g) {
        const int gc = (g << 9) + (jb << 4) + (ln & 15);
        const float v = (k < Ii) ? Wx1[k * G4c + gc] : Wh1[(k - Ii) * G4c + gc];
        Wt1[((((size_t)jb * 24 + ks) * 4 + g) * 64 + ln) * 8 + i] = (_Float16)v;
      }
    }
  } else {
    if (ln == 0 && t < 16) {
      #pragma unroll
      for (int g = 0; g < 4; ++g) {
        const int gc = (g << 9) + (jb << 4) + t;
        bc2[gc] = bx2[gc] + bh2[gc];
      }
    }
    #pragma unroll
    for (int g = 0; g < 4; ++g) {
      const int gc = (g << 9) + (jb << 4) + (ln & 15);
      const float v = (k < Hh) ? Wx2[k * G4c + gc] : Wh2[(k - Hh) * G4c + gc];
      Wt2[((((size_t)jb * 32 + ks) * 4 + g) * 64 + ln) * 8 + i] = (_Float16)v;
    }
  }
}

__global__ void zero_ws(u32x4* p, int n) {
  const int i = blockIdx.x * blockDim.x + threadIdx.x;
  if (i < n) p[i] = (u32x4){0u, 0u, 0u, 0u};
}

// Persistent cooperative kernel.
// 128 blocks: bid>>6 = layer; blkL = bid&63; jb = blkL>>1; rh = blkL&1.
// Flags: monotonic epoch counters, flag = e+1 after finishing epoch e.
// layer1@e waits [L1>=e && L2>=e-1] (3-slot h1 gives 1-epoch cross-layer slack);
// layer2@e waits [L1>=e && L2>=e]. Exchange via sc0 sc1 (memory-side coherent).
__global__ __launch_bounds__(256, 1) void lstm_main(
    const float* __restrict__ x,
    const _Float16* __restrict__ Wt1, const _Float16* __restrict__ Wt2,
    const float* __restrict__ bc1, const float* __restrict__ bc2,
    _Float16* h1buf, _Float16* h2buf, unsigned* flags,
    const float* __restrict__ Whead, const float* __restrict__ bhead,
    float* __restrict__ out)
{
  extern __shared__ char smem[];

  const int tid  = threadIdx.x;
  const int lane = tid & 63;
  const int wv   = tid >> 6;
  const int bid  = blockIdx.x;
  const int layer = bid >> 6;
  const int blkL  = bid & 63;
  const int jb = blkL >> 1;
  const int rh = blkL & 1;
  const int j0 = jb << 4;

  unsigned* grp = flags + (size_t)(rh << 6) * FSTRIDE;
  unsigned* myflag = grp + (size_t)((layer << 5) + jb) * FSTRIDE;

  // ---- stage fragment-major weight slice into LDS (flat copy) ----
  {
    const int elems16 = layer ? (131072 / 16) : (98304 / 16);
    const u32x4* src = (const u32x4*)((layer ? Wt2 : Wt1)
                                      + (size_t)jb * (layer ? 65536 : 49152));
    u32x4* dst = (u32x4*)smem;
    for (int i = tid; i < elems16; i += 256) dst[i] = src[i];
  }
  __syncthreads();

  const int c15 = lane & 15;
  const int kg  = lane >> 4;
  const int arow  = (rh << 6) + (wv << 4) + c15;
  const int wrow0 = (rh << 6) + (wv << 4) + (kg << 2);

  const float* bc = layer ? bc2 : bc1;
  const float bias0 = bc[        j0 + c15];
  const float bias1 = bc[ 512 +  j0 + c15];
  const float bias2 = bc[1024 +  j0 + c15];
  const float bias3 = bc[1536 +  j0 + c15];

  const int lb = lane << 4;

  f32x4 cst = {0.f, 0.f, 0.f, 0.f};

  int m3w = 0;   // e % 3       (h1 write slot)
  int m3r = 2;   // (e-1) % 3   (h1 read slot)

  for (int e = 0; e <= Tt; ++e) {
    if (layer == 0) {
      if (e >= Tt) break;   // layer1 done (published 512 at e=511)
      // 1. x prefetch BEFORE the wait (barrier-independent, plain cached)
      f32x4 xf[16];
      const float* xp = x + (size_t)arow * (Tt * Ii) + (size_t)e * Ii + (kg << 3);
      #pragma unroll
      for (int ks = 0; ks < 8; ++ks) {
        ld_g_f32x4(xf[2*ks],   xp + (ks << 5));
        ld_g_f32x4(xf[2*ks+1], xp + (ks << 5) + 4);
      }
      // 2. wait for producers
      poll2(grp, tid, (unsigned)e, e ? (unsigned)(e - 1) : 0u);
      // 3. h1(e-1) loads (sc0 sc1: memory-side coherent, round-5 proven)
      f16x8 af[24];
      const _Float16* hp = h1buf + (size_t)m3r * BHc + arow * Hh + (kg << 3);
      #pragma unroll
      for (int ks = 0; ks < 16; ++ks)
        ld_g_f16x8_sc(af[8 + ks], hp + (ks << 5));
      wait_vm0();
      __builtin_amdgcn_sched_barrier(0);
      #pragma unroll
      for (int ks = 0; ks < 8; ++ks) {
        f16x8 v;
        v[0] = (_Float16)xf[2*ks][0]; v[1] = (_Float16)xf[2*ks][1];
        v[2] = (_Float16)xf[2*ks][2]; v[3] = (_Float16)xf[2*ks][3];
        v[4] = (_Float16)xf[2*ks+1][0]; v[5] = (_Float16)xf[2*ks+1][1];
        v[6] = (_Float16)xf[2*ks+1][2]; v[7] = (_Float16)xf[2*ks+1][3];
        af[ks] = v;
      }
      f32x4 acc0 = {0.f,0.f,0.f,0.f}, acc1 = {0.f,0.f,0.f,0.f};
      f32x4 acc2 = {0.f,0.f,0.f,0.f}, acc3 = {0.f,0.f,0.f,0.f};
      #pragma unroll
      for (int ks = 0; ks < 24; ++ks) {
        const char* bp = smem + (ks << 12) + lb;
        acc0 = __builtin_amdgcn_mfma_f32_16x16x32_f16(af[ks], *(const f16x8*)(bp       ), acc0, 0, 0, 0);
        acc1 = __builtin_amdgcn_mfma_f32_16x16x32_f16(af[ks], *(const f16x8*)(bp + 1024), acc1, 0, 0, 0);
        acc2 = __builtin_amdgcn_mfma_f32_16x16x32_f16(af[ks], *(const f16x8*)(bp + 2048), acc2, 0, 0, 0);
        acc3 = __builtin_amdgcn_mfma_f32_16x16x32_f16(af[ks], *(const f16x8*)(bp + 3072), acc3, 0, 0, 0);
      }
      float hout[4];
      #pragma unroll
      for (int r = 0; r < 4; ++r) {
        const float iv = sigm(acc0[r] + bias0);
        const float fv = sigm(acc1[r] + bias1);
        const float gv = tanhf_(acc2[r] + bias2);
        const float ov = sigm(acc3[r] + bias3);
        const float cv = fv * cst[r] + iv * gv;
        cst[r] = cv;
        hout[r] = ov * tanhf_(cv);
      }
      _Float16* hw = h1buf + (size_t)m3w * BHc;
      #pragma unroll
      for (int r = 0; r < 4; ++r)
        st_g_f16_sc(hw + (size_t)(wrow0 + r) * Hh + j0 + c15, (_Float16)hout[r]);
      publish(myflag, tid, (unsigned)(e + 1));
    } else {
      if (e == 0) {
        publish(myflag, tid, 1u);
      } else {
        poll2(grp, tid, (unsigned)e, (unsigned)e);
        f16x8 af[32];
        const _Float16* h1p = h1buf + (size_t)m3r * BHc + arow * Hh + (kg << 3);
        const _Float16* h2p = h2buf + (size_t)(e & 1) * BHc + arow * Hh + (kg << 3);
        #pragma unroll
        for (int ks = 0; ks < 16; ++ks)
          ld_g_f16x8_sc(af[ks], h1p + (ks << 5));
        #pragma unroll
        for (int ks = 0; ks < 16; ++ks)
          ld_g_f16x8_sc(af[16 + ks], h2p + (ks << 5));
        wait_vm0();
        __builtin_amdgcn_sched_barrier(0);
        f32x4 acc0 = {0.f,0.f,0.f,0.f}, acc1 = {0.f,0.f,0.f,0.f};
        f32x4 acc2 = {0.f,0.f,0.f,0.f}, acc3 = {0.f,0.f,0.f,0.f};
        #pragma unroll
        for (int ks = 0; ks < 32; ++ks) {
          const char* bp = smem + (ks << 12) + lb;
          acc0 = __builtin_amdgcn_mfma_f32_16x16x32_f16(af[ks], *(const f16x8*)(bp       ), acc0, 0, 0, 0);
          acc1 = __builtin_amdgcn_mfma_f32_16x16x32_f16(af[ks], *(const f16x8*)(bp + 1024), acc1, 0, 0, 0);
          acc2 = __builtin_amdgcn_mfma_f32_16x16x32_f16(af[ks], *(const f16x8*)(bp + 2048), acc2, 0, 0, 0);
          acc3 = __builtin_amdgcn_mfma_f32_16x16x32_f16(af[ks], *(const f16x8*)(bp + 3072), acc3, 0, 0, 0);
        }
        float hout[4];
        #pragma unroll
        for (int r = 0; r < 4; ++r) {
          const float iv = sigm(acc0[r] + bias0);
          const float fv = sigm(acc1[r] + bias1);
          const float gv = tanhf_(acc2[r] + bias2);
          const float ov = sigm(acc3[r] + bias3);
          const float cv = fv * cst[r] + iv * gv;
          cst[r] = cv;
          hout[r] = ov * tanhf_(cv);
        }
        _Float16* hw = h2buf + (size_t)((e + 1) & 1) * BHc;
        #pragma unroll
        for (int r = 0; r < 4; ++r)
          st_g_f16_sc(hw + (size_t)(wrow0 + r) * Hh + j0 + c15, (_Float16)hout[r]);
        publish(myflag, tid, (unsigned)(e + 1));
      }
    }
    m3w = (m3w + 1 == 3) ? 0 : m3w + 1;
    m3r = (m3r + 1 == 3) ? 0 : m3r + 1;
  }

  // head: out[b][c] = h2_T[b,:] . W_head[:,c] + b_head[c]; h2_T = h2buf slot 1 (fp16)
  if (layer == 1 && jb == 0) {
    poll2(grp, tid, 0u, 513u);   // all layer2 blocks published final epoch
    const int b_ = (rh << 6) + (tid >> 2);
    const int cc = tid & 3;
    const _Float16* hr = h2buf + BHc + (size_t)b_ * Hh;
    float s = bhead[cc];
    #pragma unroll
    for (int half = 0; half < 2; ++half) {
      f16x8 hv[32];
      #pragma unroll
      for (int kk = 0; kk < 32; ++kk)
        ld_g_f16x8_sc(hv[kk], hr + (half << 8) + (kk << 3));
      wait_vm0();
      #pragma unroll
      for (int kk = 0; kk < 32; ++kk) {
        const int k = (half << 8) + (kk << 3);
        #pragma unroll
        for (int j = 0; j < 8; ++j)
          s += (float)hv[kk][j] * Whead[(k + j) * 4 + cc];
      }
    }
    out[b_ * 4 + cc] = s;
  }
}

extern "C" void kernel_launch(void* const* d_in, const int* in_sizes, int n_in,
                              void* d_out, int out_size, void* d_ws, size_t ws_size,
                              hipStream_t stream) {
  const float* x   = (const float*)d_in[0];
  const float* Wx1 = (const float*)d_in[1];
  const float* bx1 = (const float*)d_in[2];
  const float* Wh1 = (const float*)d_in[3];
  const float* bh1 = (const float*)d_in[4];
  const float* Wx2 = (const float*)d_in[5];
  const float* bx2 = (const float*)d_in[6];
  const float* Wh2 = (const float*)d_in[7];
  const float* bh2 = (const float*)d_in[8];
  const float* Whd = (const float*)d_in[9];
  const float* bhd = (const float*)d_in[10];

  char* ws = (char*)d_ws;
  _Float16* Wt1 = (_Float16*)(ws + OFF_WT1);
  _Float16* Wt2 = (_Float16*)(ws + OFF_WT2);
  float* bc1 = (float*)(ws + OFF_BC1);
  float* bc2 = (float*)(ws + OFF_BC2);
  _Float16* h1b = (_Float16*)(ws + OFF_H1);
  _Float16* h2b = (_Float16*)(ws + OFF_H2);
  unsigned* flg = (unsigned*)(ws + OFF_FLG);
  float* out = (float*)d_out;

  init_weights<<<4096, 256, 0, stream>>>(Wx1, Wh1, bx1, bh1, Wx2, Wh2, bx2, bh2,
                                         Wt1, Wt2, bc1, bc2);
  {
    u32x4* zp = (u32x4*)(ws + OFF_H1);
    const int n = (int)((OFF_END - OFF_H1) / 16);  // zero h buffers + flags
    zero_ws<<<(n + 255) / 256, 256, 0, stream>>>(zp, n);
  }
  (void)hipFuncSetAttribute((const void*)lstm_main,
                            hipFuncAttributeMaxDynamicSharedMemorySize, 131072);
  void* args[] = {(void*)&x, (void*)&Wt1, (void*)&Wt2, (void*)&bc1, (void*)&bc2,
                  (void*)&h1b, (void*)&h2b, (void*)&flg,
                  (void*)&Whd, (void*)&bhd, (void*)&out};
  (void)hipLaunchCooperativeKernel((const void*)lstm_main, dim3(128), dim3(256),
                                   args, 131072, stream);
}